// Round 1
// baseline (24.900 us; speedup 1.0000x reference)
//
#include <hip/hip_runtime.h>

#define NB 4   // BATCH

__global__ __launch_bounds__(256) void render_cov2d_kernel(
    const int*   __restrict__ indexes,   // [NB]
    const float* __restrict__ xyz,       // [N,3]
    const float* __restrict__ scales,    // [N,3]
    const float* __restrict__ quats,     // [N,4]
    const float* __restrict__ tf,        // [8,4,4]
    const float* __restrict__ focal,     // [8,2]
    const float* __restrict__ widths,    // [8]
    float*       __restrict__ out,       // [NB,N,2,2]
    int N)
{
    int n = blockIdx.x * blockDim.x + threadIdx.x;
    if (n >= N) return;

    // ---- per-gaussian loads ----
    float px = xyz[3*n+0], py = xyz[3*n+1], pz = xyz[3*n+2];
    float sx = scales[3*n+0], sy = scales[3*n+1], sz = scales[3*n+2];
    float4 q = *reinterpret_cast<const float4*>(quats + 4*(size_t)n);

    // ---- quat -> rotation matrix ----
    float qn = rsqrtf(q.x*q.x + q.y*q.y + q.z*q.z + q.w*q.w);
    float r = q.x*qn, x = q.y*qn, y = q.z*qn, z = q.w*qn;
    float R00 = 1.f - 2.f*(y*y + z*z), R01 = 2.f*(x*y - r*z), R02 = 2.f*(x*z + r*y);
    float R10 = 2.f*(x*y + r*z), R11 = 1.f - 2.f*(x*x + z*z), R12 = 2.f*(y*z - r*x);
    float R20 = 2.f*(x*z - r*y), R21 = 2.f*(y*z + r*x), R22 = 1.f - 2.f*(x*x + y*y);

    // ---- L = R * diag(scales); cov3d = L L^T (symmetric, 6 uniques) ----
    float L00=R00*sx, L01=R01*sy, L02=R02*sz;
    float L10=R10*sx, L11=R11*sy, L12=R12*sz;
    float L20=R20*sx, L21=R21*sy, L22=R22*sz;

    float C00 = L00*L00 + L01*L01 + L02*L02;
    float C01 = L00*L10 + L01*L11 + L02*L12;
    float C02 = L00*L20 + L01*L21 + L02*L22;
    float C11 = L10*L10 + L11*L11 + L12*L12;
    float C12 = L10*L20 + L11*L21 + L12*L22;
    float C22 = L20*L20 + L21*L21 + L22*L22;

    #pragma unroll
    for (int b = 0; b < NB; ++b) {
        // camera params: uniform addresses -> scalar loads, L1-resident
        int cam = indexes[b];
        const float* T4 = tf + cam*16;
        float A00=T4[0], A01=T4[1], A02=T4[2],  t0=T4[3];
        float A10=T4[4], A11=T4[5], A12=T4[6],  t1=T4[7];
        float A20=T4[8], A21=T4[9], A22=T4[10], t2=T4[11];
        float fx = focal[cam*2+0], fy = focal[cam*2+1];
        float wid = widths[cam];
        float limx = 0.65f * wid / fx;   // 1.3 * 0.5 * wid / fx
        float limy = 0.65f * wid / fy;

        // mean in camera frame
        float mx = A00*px + A01*py + A02*pz + t0;
        float my = A10*px + A11*py + A12*pz + t1;
        float mz = A20*px + A21*py + A22*pz + t2;

        float invz = 1.f / mz;
        float cx = fminf(fmaxf(mx*invz, -limx), limx) * mz;
        float cy = fminf(fmaxf(my*invz, -limy), limy) * mz;

        // J rows: [fx/z, 0, -fx*cx/z^2], [0, fy/z, -fy*cy/z^2]
        float a0 = fx * invz;
        float a2 = -fx * cx * invz * invz;
        float b1 = fy * invz;
        float b2 = -fy * cy * invz * invz;

        // T = J @ Rcw  (2x3)
        float T00 = a0*A00 + a2*A20;
        float T01 = a0*A01 + a2*A21;
        float T02 = a0*A02 + a2*A22;
        float T10 = b1*A10 + b2*A20;
        float T11 = b1*A11 + b2*A21;
        float T12 = b1*A12 + b2*A22;

        // M = T @ C  (2x3), then cov2d = M @ T^T (symmetric 2x2)
        float M00 = T00*C00 + T01*C01 + T02*C02;
        float M01 = T00*C01 + T01*C11 + T02*C12;
        float M02 = T00*C02 + T01*C12 + T02*C22;
        float M10 = T10*C00 + T11*C01 + T12*C02;
        float M11 = T10*C01 + T11*C11 + T12*C12;
        float M12 = T10*C02 + T11*C12 + T12*C22;

        float o00 = M00*T00 + M01*T01 + M02*T02;
        float o01 = M00*T10 + M01*T11 + M02*T12;
        float o11 = M10*T10 + M11*T11 + M12*T12;

        *reinterpret_cast<float4*>(out + ((size_t)b*N + n)*4) =
            make_float4(o00, o01, o01, o11);
    }
}

extern "C" void kernel_launch(void* const* d_in, const int* in_sizes, int n_in,
                              void* d_out, int out_size, void* d_ws, size_t ws_size,
                              hipStream_t stream) {
    const int*   indexes = (const int*)  d_in[0];
    const float* xyz     = (const float*)d_in[1];
    const float* scales  = (const float*)d_in[2];
    const float* quats   = (const float*)d_in[3];
    const float* tf      = (const float*)d_in[4];
    const float* focal   = (const float*)d_in[5];
    const float* widths  = (const float*)d_in[6];
    float*       out     = (float*)d_out;

    int N = in_sizes[1] / 3;   // N_GAUSS
    int block = 256;
    int grid = (N + block - 1) / block;
    render_cov2d_kernel<<<grid, block, 0, stream>>>(
        indexes, xyz, scales, quats, tf, focal, widths, out, N);
}